// Round 8
// baseline (298.694 us; speedup 1.0000x reference)
//
#include <hip/hip_runtime.h>
#include <math.h>

#define TOK_PER_BLK 4
#define THREADS 256
#define NROWS 24
#define PCOL 68        // 64 partials + 4 pad
#define TAU_INV 20.0f  // 1/0.05

typedef _Float16 half2_t __attribute__((ext_vector_type(2)));

// ---------------------------------------------------------------------------
// Stage 0: fold (1+gamma) into the 24 weight rows, f16 pairs, PERMUTED so in
// kernel A thread tid's two uint4 loads deliver the 16 k-elements matching
// its x quads (k = q*1024 + 4*tid .. +3, q = 0..3).  (unchanged from R11)
// ---------------------------------------------------------------------------
__global__ void fold_gamma(const float* __restrict__ w_res,
                           const float* __restrict__ w_pre,
                           const float* __restrict__ w_post,
                           const float* __restrict__ gamma,
                           unsigned int* __restrict__ wf) {
    const int idx = blockIdx.x * THREADS + threadIdx.x;   // 0 .. 24*2048-1
    const int row = idx >> 11;
    const int j   = idx & 2047;
    const int o   = j >> 2;
    const int pp  = j & 3;
    const int t   = o & 255;
    const int quad = pp >> 1;
    int base;
    if (o < 256) base = (quad == 0) ? (4 * t)        : (1024 + 4 * t);
    else         base = (quad == 0) ? (2048 + 4 * t) : (3072 + 4 * t);
    const int k0 = base + 2 * (pp & 1);

    const float* src = (row < 16) ? (w_res + ((size_t)row << 12))
                     : (row < 20) ? (w_pre + ((size_t)(row - 16) << 12))
                                  : (w_post + ((size_t)(row - 20) << 12));
    float v0 = src[k0]     * (1.0f + gamma[k0]);
    float v1 = src[k0 + 1] * (1.0f + gamma[k0 + 1]);
    union { _Float16 h[2]; unsigned int u; } cvt;
    cvt.h[0] = (_Float16)v0;
    cvt.h[1] = (_Float16)v1;
    wf[idx] = cvt.u;
}

// ---------------------------------------------------------------------------
// R12 SPLIT. R11 post-mortem: fused kernel stuck at 115us with ALL pipes <30%
// (VALU 27, HBM 22, occ 57) -> block wall-life 33us vs 3.5us issue. The fused
// barrier+serial-sinkhorn critical path convoys every wave. Split into:
//   A: dots only (this kernel) -> raw[tok][32] workspace. Block ends at reduce.
//   B: sinkhorn/gates, 16 lanes per token, 4 tokens/wave -> M[tok][16].
//   C: streaming apply out = M.x, one block per token, pure BW.
// ---------------------------------------------------------------------------
__global__ __launch_bounds__(THREADS, 2)   // (256,2): allocator spills toward
void hc_dots(const float* __restrict__ resid,          // 2x declared min-waves
             const unsigned int* __restrict__ wf,      // (R4/R5/R7/R8 evidence)
             float* __restrict__ g_raw)
{
    __shared__ __align__(16) float sh_part[NROWS * TOK_PER_BLK][PCOL]; // 26.1 KB
    __shared__ __align__(16) float sh_ssqp[TOK_PER_BLK][PCOL];

    const int tid  = threadIdx.x;
    const int wave = tid >> 6;
    const int lane = tid & 63;
    const long tok0 = (long)blockIdx.x * TOK_PER_BLK;

    // ---- Phase 1: global -> fp32 sumsq -> packed f16 registers ----
    const float4* hp = (const float4*)resid + tok0 * 1024;
    half2_t xh[TOK_PER_BLK][8];
    #pragma unroll
    for (int m = 0; m < TOK_PER_BLK; ++m) {
        float4 pf[4];
        #pragma unroll
        for (int q = 0; q < 4; ++q)
            pf[q] = hp[m * 1024 + q * 256 + tid];
        float s = 0.f;
        #pragma unroll
        for (int q = 0; q < 4; ++q) {
            float4 v = pf[q];
            s += v.x * v.x + v.y * v.y + v.z * v.z + v.w * v.w;
            xh[m][2 * q]     = half2_t{(_Float16)v.x, (_Float16)v.y};
            xh[m][2 * q + 1] = half2_t{(_Float16)v.z, (_Float16)v.w};
        }
        s += __shfl_xor(s, 16, 64);
        s += __shfl_xor(s, 32, 64);
        if (lane < 16) sh_ssqp[m][wave * 16 + lane] = s;
    }

    // ---- Phase 2: 24 dots via fdot2, depth-2 (triple) prefetch ----
    const uint4* wp = (const uint4*)wf;      // 512 uint4 per row

    auto load_row = [&](int e, uint4 (&w)[2]) {
        const uint4* wr = wp + ((size_t)e << 9);
        w[0] = wr[tid];
        w[1] = wr[256 + tid];
    };
#define H2(u) __builtin_bit_cast(half2_t, (u))
    auto comp_row = [&](int e, const uint4 (&W)[2]) {
        #pragma unroll
        for (int m = 0; m < TOK_PER_BLK; ++m) {
            float a = 0.f;
            a = __builtin_amdgcn_fdot2(H2(W[0].x), xh[m][0], a, false);
            a = __builtin_amdgcn_fdot2(H2(W[0].y), xh[m][1], a, false);
            a = __builtin_amdgcn_fdot2(H2(W[0].z), xh[m][2], a, false);
            a = __builtin_amdgcn_fdot2(H2(W[0].w), xh[m][3], a, false);
            a = __builtin_amdgcn_fdot2(H2(W[1].x), xh[m][4], a, false);
            a = __builtin_amdgcn_fdot2(H2(W[1].y), xh[m][5], a, false);
            a = __builtin_amdgcn_fdot2(H2(W[1].z), xh[m][6], a, false);
            a = __builtin_amdgcn_fdot2(H2(W[1].w), xh[m][7], a, false);
            a += __shfl_xor(a, 16, 64);
            a += __shfl_xor(a, 32, 64);
            if (lane < 16) sh_part[e * TOK_PER_BLK + m][wave * 16 + lane] = a;
        }
    };
#undef H2

    uint4 wA[2], wB[2], wC[2];
    load_row(0, wA);
    load_row(1, wB);
    #pragma unroll 1
    for (int c = 0; c < 8; ++c) {            // rows 3c, 3c+1, 3c+2
        load_row(3 * c + 2, wC);
        comp_row(3 * c, wA);
        if (3 * c + 3 < NROWS) load_row(3 * c + 3, wA);
        comp_row(3 * c + 1, wB);
        if (3 * c + 4 < NROWS) load_row(3 * c + 4, wB);
        comp_row(3 * c + 2, wC);
    }
    __syncthreads();

    // ---- Reduce + store raw (block ends here; no sinkhorn, no apply) ----
    if (tid < NROWS * TOK_PER_BLK) {           // 96 threads: one (row,token)
        const int e = tid >> 2, m = tid & 3;
        const float4* src = (const float4*)&sh_part[e * TOK_PER_BLK + m][0];
        float4 s4 = src[0];
        #pragma unroll
        for (int j = 1; j < 16; ++j) {
            float4 v = src[j];
            s4.x += v.x; s4.y += v.y; s4.z += v.z; s4.w += v.w;
        }
        g_raw[(tok0 + m) * 32 + e] = s4.x + s4.y + s4.z + s4.w;
    } else if (tid < NROWS * TOK_PER_BLK + TOK_PER_BLK) {
        const int m = tid - NROWS * TOK_PER_BLK;
        const float4* src = (const float4*)&sh_ssqp[m][0];
        float4 s4 = src[0];
        #pragma unroll
        for (int j = 1; j < 16; ++j) {
            float4 v = src[j];
            s4.x += v.x; s4.y += v.y; s4.z += v.z; s4.w += v.w;
        }
        g_raw[(tok0 + m) * 32 + 24] = s4.x + s4.y + s4.z + s4.w;
    }
}

// ---------------------------------------------------------------------------
// Kernel B: sinkhorn + gates. Each 16-lane group owns one token (4 tokens per
// wave run their serial chains in PARALLEL: all shuffles xor 1,2,4,8 are
// group-local). Emits combined M[i][j] = Hres[i][j] + Hpost[i]*Hpre[j].
// ---------------------------------------------------------------------------
__global__ void hc_sinkhorn(const float* __restrict__ g_raw,
                            const float* __restrict__ beta_res,
                            const float* __restrict__ beta_pre,
                            const float* __restrict__ beta_post,
                            const float* __restrict__ p_alpha_res,
                            const float* __restrict__ p_alpha_pre,
                            const float* __restrict__ p_alpha_post,
                            float* __restrict__ g_M)
{
    const int tid  = threadIdx.x;
    const int wave = tid >> 6;
    const int lane = tid & 63;
    const int grp  = lane >> 4;          // 4 token-groups per wave
    const int idx  = lane & 15;          // (i,j): i = idx>>2, j = idx&3
    const int jj   = idx & 3;
    const long t   = (long)blockIdx.x * 16 + wave * 4 + grp;

    const float* rp = g_raw + t * 32;
    float ss    = rp[24];
    float scale = 64.0f / fmaxf(sqrtf(ss), 1e-12f);

    const float a_res  = p_alpha_res[0];
    const float a_pre  = p_alpha_pre[0];
    const float a_post = p_alpha_post[0];

    float Z = (beta_res[idx] + a_res * scale * rp[idx]) * TAU_INV;
    float u = 0.f, v = 0.f;
    #pragma unroll 1
    for (int it = 0; it < 10; ++it) {
        float tv = Z + v;
        float mx = tv;
        mx = fmaxf(mx, __shfl_xor(mx, 1, 64));
        mx = fmaxf(mx, __shfl_xor(mx, 2, 64));
        float sm = __expf(tv - mx);
        sm += __shfl_xor(sm, 1, 64);
        sm += __shfl_xor(sm, 2, 64);
        u = -(mx + __logf(sm));
        tv = Z + u;
        mx = tv;
        mx = fmaxf(mx, __shfl_xor(mx, 4, 64));
        mx = fmaxf(mx, __shfl_xor(mx, 8, 64));
        sm = __expf(tv - mx);
        sm += __shfl_xor(sm, 4, 64);
        sm += __shfl_xor(sm, 8, 64);
        v = -(mx + __logf(sm));
    }
    float P = __expf(Z + u + v);             // Hres[i][j]

    float lpre = beta_pre[jj] + a_pre * scale * rp[16 + jj];
    float mxp = lpre;
    mxp = fmaxf(mxp, __shfl_xor(mxp, 1, 64));
    mxp = fmaxf(mxp, __shfl_xor(mxp, 2, 64));
    float ep = __expf(lpre - mxp);
    float sp = ep;
    sp += __shfl_xor(sp, 1, 64);
    sp += __shfl_xor(sp, 2, 64);
    float hpre = ep / sp;                    // Hpre[jj]
    float lpost = beta_post[jj] + a_post * scale * rp[20 + jj];
    float hpost = 2.0f / (1.0f + __expf(-lpost));  // Hpost[jj]

    // Hpost[i]: lane (group_base | i) computed hpost for jj == i.
    float hpost_i = __shfl(hpost, (lane & 48) | (idx >> 2), 64);
    g_M[t * 16 + idx] = P + hpost_i * hpre;
}

// ---------------------------------------------------------------------------
// Kernel C: streaming apply. One block per token: stage M (16 floats) in LDS,
// out[i][d] = sum_j M[i][j] * x[j][d]. Pure coalesced stream, fp32 end to end
// (MORE accurate than R11's f16 phase 4).
// ---------------------------------------------------------------------------
__global__ void hc_apply(const float* __restrict__ resid,
                         const float* __restrict__ g_M,
                         float* __restrict__ out)
{
    __shared__ float sh_M[16];
    const int tid = threadIdx.x;
    const long t  = blockIdx.x;

    if (tid < 16) sh_M[tid] = g_M[t * 16 + tid];
    __syncthreads();

    const float4* xp = (const float4*)resid + t * 1024;
    float4 x0 = xp[tid], x1 = xp[256 + tid], x2 = xp[512 + tid], x3 = xp[768 + tid];

    float Mv[16];
    #pragma unroll
    for (int k = 0; k < 16; ++k) Mv[k] = sh_M[k];

    float4* op = (float4*)out + t * 1024;
    #pragma unroll
    for (int i = 0; i < 4; ++i) {
        float4 o;
        o.x = Mv[i*4+0]*x0.x + Mv[i*4+1]*x1.x + Mv[i*4+2]*x2.x + Mv[i*4+3]*x3.x;
        o.y = Mv[i*4+0]*x0.y + Mv[i*4+1]*x1.y + Mv[i*4+2]*x2.y + Mv[i*4+3]*x3.y;
        o.z = Mv[i*4+0]*x0.z + Mv[i*4+1]*x1.z + Mv[i*4+2]*x2.z + Mv[i*4+3]*x3.z;
        o.w = Mv[i*4+0]*x0.w + Mv[i*4+1]*x1.w + Mv[i*4+2]*x2.w + Mv[i*4+3]*x3.w;
        op[i * 256 + tid] = o;
    }
}

extern "C" void kernel_launch(void* const* d_in, const int* in_sizes, int n_in,
                              void* d_out, int out_size, void* d_ws, size_t ws_size,
                              hipStream_t stream) {
    const float* resid      = (const float*)d_in[0];
    const float* gamma      = (const float*)d_in[1];
    const float* w_res      = (const float*)d_in[2];
    const float* w_pre      = (const float*)d_in[3];
    const float* w_post     = (const float*)d_in[4];
    const float* beta_res   = (const float*)d_in[5];
    const float* beta_pre   = (const float*)d_in[6];
    const float* beta_post  = (const float*)d_in[7];
    const float* alpha_res  = (const float*)d_in[8];
    const float* alpha_pre  = (const float*)d_in[9];
    const float* alpha_post = (const float*)d_in[10];
    float* out = (float*)d_out;

    const int ntok = in_sizes[0] / 4096;          // B*T = 8192

    // Workspace layout: wf 192KB | raw ntok*32*4 = 1MB | M ntok*16*4 = 512KB
    char* ws = (char*)d_ws;
    unsigned int* wf  = (unsigned int*)ws;
    float* g_raw      = (float*)(ws + 192 * 1024);
    float* g_M        = (float*)(ws + 192 * 1024 + (size_t)ntok * 32 * 4);
    (void)ws_size;

    fold_gamma<<<NROWS * 2048 / THREADS, THREADS, 0, stream>>>(
        w_res, w_pre, w_post, gamma, wf);

    hc_dots<<<ntok / TOK_PER_BLK, THREADS, 0, stream>>>(resid, wf, g_raw);

    hc_sinkhorn<<<ntok / 16, THREADS, 0, stream>>>(
        g_raw, beta_res, beta_pre, beta_post,
        alpha_res, alpha_pre, alpha_post, g_M);

    hc_apply<<<ntok, THREADS, 0, stream>>>(resid, g_M, out);
}